// Round 14
// baseline (100.875 us; speedup 1.0000x reference)
//
#include <hip/hip_runtime.h>
#include <hip/hip_bf16.h>

// ---------------------------------------------------------------------------
// TT-linear, rank-64 factorized, 2 launches:
//   tt_chain_fused : cores -> A4f, B4f (both MFMA-fragment-ordered bf16)
//   tt_gemm_fused  : per block (16 rows, 16 waves, 2 blocks/CU):
//     phase1: z = x_rows @ A4 (r12's proven split-K body, z -> LDS bf16)
//     phase2: out_rows = z @ B4 + bias — zero barriers AND coalesced stores:
//             operand-SWAPPED MFMA (mfma(B4_frag, z_frag)) yields the
//             transposed C fragment, so each lane holds 4 CONTIGUOUS output
//             cols of one row -> single f32x4 store. No LDS, no fences.
//     (r13 lost ~15us to 4-rows-per-lane scalar stores; r9 lost to
//      barrier-per-2-MFMA staging. This removes both.)
// HBM/L3 floor: read x 131 MB + write out 134 MB ~= 42 us.
// Lesson bank: no nt hints (r10); no forced-occupancy pipelines (r11);
// no barrier-per-2-MFMA staging (r9); occupancy arithmetic first (r5).
// ---------------------------------------------------------------------------

typedef __attribute__((ext_vector_type(8))) short short8;
typedef __attribute__((ext_vector_type(4))) short s16x4;
typedef __attribute__((ext_vector_type(4))) float f32x4;

__device__ __forceinline__ short f2bf(float f) {
    union { float f; unsigned u; } c; c.f = f;
    unsigned u = c.u;
    unsigned r = (u + 0x7fffu + ((u >> 16) & 1u)) >> 16;  // RNE
    return (short)r;
}

// ---------------- chain: all 6 stages, 1 launch, 1536 x 256 (proven r13) ----
// A-side blocks [0,1024): A4f fragment-ordered:
//   A4[k][s] at [((k>>5)*4+(s>>4))*512 + ((k>>3)&3)*128 + (s&15)*8 + (k&7)]
// B-side blocks [1024,1536): B4f fragment-ordered:
//   B4[r4][n] at [((n>>4)*2+(r4>>5))*512 + ((r4>>3)&3)*128 + (n&15)*8 + (r4&7)]
//   so phase2's b-load for (colfrag fi, khalf h) is lane-contiguous:
//   B4f + fi*1024 + h*512 + lane*8
__global__ __launch_bounds__(256) void tt_chain_fused(
    const float* __restrict__ c0, const float* __restrict__ c1,
    const float* __restrict__ c2, const float* __restrict__ c3,
    const float* __restrict__ c4, const float* __restrict__ c5,
    const float* __restrict__ c6, const float* __restrict__ c7,
    short* __restrict__ A4f, short* __restrict__ B4f) {
    __shared__ float sm[1024];
    const int t = threadIdx.x;
    if (blockIdx.x < 1024) {
        const int bid = blockIdx.x;
        const int i = bid >> 1;          // A3 row
        const int a2r = bid >> 4;        // A2 row
        float* A2r_ = sm;                // 64
        float* A3r_ = sm + 64;           // 64
        if (t < 64) {
            const int i1 = a2r >> 3, d1 = a2r & 7;
            float acc = 0.f;
            for (int r = 0; r < 64; ++r)
                acc += c0[i1 * 64 + r] * c1[(r * 8 + d1) * 64 + t];
            A2r_[t] = acc;
        }
        __syncthreads();
        if (t < 64) {
            const int d2 = i & 7;
            float acc = 0.f;
            for (int r = 0; r < 64; ++r)
                acc += A2r_[r] * c2[(r * 8 + d2) * 64 + t];
            A3r_[t] = acc;
        }
        __syncthreads();
        {
            const int kk = t >> 6, s = t & 63;
            const int k = (bid << 2) + kk, d3 = k & 7;
            float acc = 0.f;
            for (int r = 0; r < 64; ++r)
                acc += A3r_[r] * c3[(r * 8 + d3) * 64 + s];
            A4f[(((k >> 5) * 4 + (s >> 4)) << 9) + (((k >> 3) & 3) << 7) +
                ((s & 15) << 3) + (k & 7)] = f2bf(acc);
        }
    } else {
        const int cb = blockIdx.x - 1024;       // [0,512)
        const int d4 = cb & 7, jgrp = cb >> 3;  // jgrp in [0,64)
        const int d5 = jgrp >> 3;
        const int d6 = jgrp & 7;
        float* B6l = sm;         // [q6*8 + jj] = B6[q6][d6*8+jj]
        float* B5l = sm + 512;   // [q5*8 + jj] = B5[q5][jgrp*8+jj]
        for (int o = t; o < 512; o += 256) {
            const int q6 = o >> 3, jj = o & 7;
            float acc = 0.f;
            for (int q7 = 0; q7 < 64; ++q7)
                acc += c6[(q6 * 8 + d6) * 64 + q7] * c7[q7 * 8 + jj];
            B6l[o] = acc;
        }
        __syncthreads();
        for (int o = t; o < 512; o += 256) {
            const int q5 = o >> 3, jj = o & 7;
            float acc = 0.f;
            for (int q6 = 0; q6 < 64; ++q6)
                acc += c5[(q5 * 8 + d5) * 64 + q6] * B6l[q6 * 8 + jj];
            B5l[o] = acc;
        }
        __syncthreads();
        for (int o = t; o < 512; o += 256) {
            const int nl = o >> 6, r4 = o & 63;
            float acc = 0.f;
            for (int q5 = 0; q5 < 64; ++q5)
                acc += c4[(r4 * 8 + d4) * 64 + q5] * B5l[q5 * 8 + nl];
            const int n = d4 * 512 + jgrp * 8 + nl;
            B4f[(((n >> 4) * 2 + (r4 >> 5)) << 9) + (((r4 >> 3) & 3) << 7) +
                ((n & 15) << 3) + (r4 & 7)] = f2bf(acc);
        }
    }
}

// ---------------- fused GEMM: out rows = ((x rows) @ A4) @ B4 + bias --------
// 512 blocks x 1024 threads (16 waves), 2 blocks/CU (66 KB LDS, <=64 VGPR).
__global__ __launch_bounds__(1024, 8) void tt_gemm_fused(
    const float* __restrict__ x, const short* __restrict__ A4f,
    const short* __restrict__ B4f, const float* __restrict__ bias,
    float* __restrict__ out) {
    __shared__ float zsm[16 * 1024];  // 64 KB: [wave][row16][col64]
    __shared__ short zbl[16 * 64];    // 2 KB: z in bf16
    const int tid = threadIdx.x, wave = tid >> 6, lane = tid & 63;
    const int m0 = blockIdx.x << 4;
    const int r16 = lane & 15, hi = lane >> 4, kq = hi << 3;

    // ---- phase 1: z = x[m0..m0+16) @ A4 (r12's proven gemm1_v2 body) ----
    {
        const float* xp = x + (long)(m0 + r16) * 4000 + kq;
        const short* a4p = A4f + (lane << 3);
        f32x4 acc[4] = {};
#pragma unroll 2
        for (int t = wave; t < 125; t += 16) {
            const int k0 = t << 5;
            f32x4 u0 = *(const f32x4*)(xp + k0);
            f32x4 u1 = *(const f32x4*)(xp + k0 + 4);
            short8 a;
            a[0] = f2bf(u0[0]); a[1] = f2bf(u0[1]);
            a[2] = f2bf(u0[2]); a[3] = f2bf(u0[3]);
            a[4] = f2bf(u1[0]); a[5] = f2bf(u1[1]);
            a[6] = f2bf(u1[2]); a[7] = f2bf(u1[3]);
#pragma unroll
            for (int f = 0; f < 4; ++f) {
                short8 b = *(const short8*)(a4p + (((t << 2) + f) << 9));
                acc[f] = __builtin_amdgcn_mfma_f32_16x16x32_bf16(a, b, acc[f], 0, 0, 0);
            }
        }
        // C/D layout: col = f*16 + (lane&15), row = (lane>>4)*4 + u
        const int prow = hi << 2;
#pragma unroll
        for (int f = 0; f < 4; ++f)
#pragma unroll
            for (int u = 0; u < 4; ++u)
                zsm[wave * 1024 + (prow + u) * 64 + f * 16 + r16] = acc[f][u];
    }
    __syncthreads();
    if (tid < 256) {
        const f32x4* zp = (const f32x4*)zsm;  // 256 f32x4 per wave-slab
        f32x4 s = zp[tid];
#pragma unroll
        for (int w = 1; w < 16; ++w) s += zp[w * 256 + tid];
        s16x4 o;
#pragma unroll
        for (int u = 0; u < 4; ++u) o[u] = f2bf(s[u]);
        *(s16x4*)(zbl + (tid >> 4) * 64 + ((tid & 15) << 2)) = o;
    }
    __syncthreads();

    // ---- phase 2: out = z @ B4 + bias — zero barriers, swapped MFMA ----
    // az: lane&15 = z row r, k = h*32 + hi*8 + e.  b: lane&15 = col n within
    // fragment fi, k = h*32 + hi*8 + e.  mfma(b, az) -> D^T fragment:
    // lane (hi,r16), reg u = out[m0+r16][fi*16 + hi*4 + u]  (u contiguous!)
    const short8 az0 = *(const short8*)(zbl + r16 * 64 + kq);       // k 0..32
    const short8 az1 = *(const short8*)(zbl + r16 * 64 + 32 + kq);  // k 32..64
    const long rowbase = (long)(m0 + r16) * 4096;
#pragma unroll 4
    for (int c = 0; c < 16; ++c) {
        const int fi = (wave << 4) + c;               // col-fragment 0..255
        const short* bp = B4f + (fi << 10) + (lane << 3);
        const short8 b0 = *(const short8*)(bp);       // k-half 0, 1KB/wave
        const short8 b1 = *(const short8*)(bp + 512); // k-half 1
        f32x4 a = {};
        a = __builtin_amdgcn_mfma_f32_16x16x32_bf16(b0, az0, a, 0, 0, 0);
        a = __builtin_amdgcn_mfma_f32_16x16x32_bf16(b1, az1, a, 0, 0, 0);
        const int col0 = (fi << 4) + (hi << 2);
        f32x4 v = *(const f32x4*)(bias + col0);
        v += a;
        *(f32x4*)(out + rowbase + col0) = v;
    }
}

// ---------------------------------------------------------------------------
extern "C" void kernel_launch(void* const* d_in, const int* in_sizes, int n_in,
                              void* d_out, int out_size, void* d_ws, size_t ws_size,
                              hipStream_t stream) {
    const float* x    = (const float*)d_in[0];
    const float* c0   = (const float*)d_in[1];
    const float* c1   = (const float*)d_in[2];
    const float* c2   = (const float*)d_in[3];
    const float* c3   = (const float*)d_in[4];
    const float* c4   = (const float*)d_in[5];
    const float* c5   = (const float*)d_in[6];
    const float* c6   = (const float*)d_in[7];
    const float* c7   = (const float*)d_in[8];
    const float* bias = (const float*)d_in[9];
    float* out = (float*)d_out;

    char* ws = (char*)d_ws;
    short* A4f = (short*)ws;                      // 64*4096*2 = 512 KiB (frag-ordered)
    short* B4f = (short*)(ws + (512u << 10));     // 64*4096*2 = 512 KiB (frag-ordered)

    tt_chain_fused<<<1536, 256, 0, stream>>>(c0, c1, c2, c3, c4, c5, c6, c7,
                                             A4f, B4f);
    tt_gemm_fused<<<512, 1024, 0, stream>>>(x, A4f, B4f, bias, out);
}

// Round 15
// 83.353 us; speedup vs baseline: 1.2102x; 1.2102x over previous
//
#include <hip/hip_runtime.h>
#include <hip/hip_bf16.h>

// ---------------------------------------------------------------------------
// TT-linear, rank-64 factorized, 3 launches (best-known config = round 12):
//   tt_chain_fused : cores -> A4f (MFMA-fragment-ordered bf16), B4t (4096x64)
//   GEMM1          : zb[8192x64] = x @ A4; 512 x 1024, 2 blocks/CU (45 VGPR)
//   GEMM2          : out = zb @ B4t^T + bias, K=64; global_load_lds staging,
//                    barriered LDS-transpose epilogue (256B store segments)
// HBM floor: read x 131 MB + write out 134 MB ~= 42 us.  Measured best: 82.5.
// Lesson bank (all measured): no nt hints (r10 +10us); no forced-occupancy
// pipelines (r11 VGPR spill +15us); no barrier-per-2-MFMA staging (r9 +17us);
// no phase-fused single kernel (r13/r14 +15-18us: co-resident blocks
// serialize read/write phases chip-wide); no 2-block chains (r3 +100us).
// ---------------------------------------------------------------------------

typedef __attribute__((ext_vector_type(8))) short short8;
typedef __attribute__((ext_vector_type(4))) short s16x4;
typedef __attribute__((ext_vector_type(4))) float f32x4;

__device__ __forceinline__ short f2bf(float f) {
    union { float f; unsigned u; } c; c.f = f;
    unsigned u = c.u;
    unsigned r = (u + 0x7fffu + ((u >> 16) & 1u)) >> 16;  // RNE
    return (short)r;
}

// ---------------- chain: all 6 stages, 1 launch, 1536 x 256 -----------------
__global__ __launch_bounds__(256) void tt_chain_fused(
    const float* __restrict__ c0, const float* __restrict__ c1,
    const float* __restrict__ c2, const float* __restrict__ c3,
    const float* __restrict__ c4, const float* __restrict__ c5,
    const float* __restrict__ c6, const float* __restrict__ c7,
    short* __restrict__ A4f, short* __restrict__ B4t) {
    __shared__ float sm[1024];
    const int t = threadIdx.x;
    if (blockIdx.x < 1024) {
        const int bid = blockIdx.x;
        const int i = bid >> 1;          // A3 row
        const int a2r = bid >> 4;        // A2 row
        float* A2r_ = sm;                // 64
        float* A3r_ = sm + 64;           // 64
        if (t < 64) {
            const int i1 = a2r >> 3, d1 = a2r & 7;
            float acc = 0.f;
            for (int r = 0; r < 64; ++r)
                acc += c0[i1 * 64 + r] * c1[(r * 8 + d1) * 64 + t];
            A2r_[t] = acc;
        }
        __syncthreads();
        if (t < 64) {
            const int d2 = i & 7;
            float acc = 0.f;
            for (int r = 0; r < 64; ++r)
                acc += A2r_[r] * c2[(r * 8 + d2) * 64 + t];
            A3r_[t] = acc;
        }
        __syncthreads();
        {
            const int kk = t >> 6, s = t & 63;
            const int k = (bid << 2) + kk, d3 = k & 7;
            float acc = 0.f;
            for (int r = 0; r < 64; ++r)
                acc += A3r_[r] * c3[(r * 8 + d3) * 64 + s];
            A4f[(((k >> 5) * 4 + (s >> 4)) << 9) + (((k >> 3) & 3) << 7) +
                ((s & 15) << 3) + (k & 7)] = f2bf(acc);
        }
    } else {
        const int cb = blockIdx.x - 1024;       // [0,512)
        const int d4 = cb & 7, jgrp = cb >> 3;  // jgrp in [0,64)
        const int d5 = jgrp >> 3;
        const int d6 = jgrp & 7;
        float* B6l = sm;         // [q6*8 + jj] = B6[q6][d6*8+jj]
        float* B5l = sm + 512;   // [q5*8 + jj] = B5[q5][jgrp*8+jj]
        for (int o = t; o < 512; o += 256) {
            const int q6 = o >> 3, jj = o & 7;
            float acc = 0.f;
            for (int q7 = 0; q7 < 64; ++q7)
                acc += c6[(q6 * 8 + d6) * 64 + q7] * c7[q7 * 8 + jj];
            B6l[o] = acc;
        }
        __syncthreads();
        for (int o = t; o < 512; o += 256) {
            const int q5 = o >> 3, jj = o & 7;
            float acc = 0.f;
            for (int q6 = 0; q6 < 64; ++q6)
                acc += c5[(q5 * 8 + d5) * 64 + q6] * B6l[q6 * 8 + jj];
            B5l[o] = acc;
        }
        __syncthreads();
        for (int o = t; o < 512; o += 256) {
            const int nl = o >> 6, r4 = o & 63;
            float acc = 0.f;
            for (int q5 = 0; q5 < 64; ++q5)
                acc += c4[(r4 * 8 + d4) * 64 + q5] * B5l[q5 * 8 + nl];
            const int n = d4 * 512 + jgrp * 8 + nl;
            B4t[n * 64 + r4] = f2bf(acc);
        }
    }
}

// ---------------- GEMM1: zb = f2bf(x @ A4), 512 blocks x 1024 threads -------
// Block owns 16 rows; 16 waves split the 125 k-tiles (4000 = 125*32);
// f32 partials reduced through 64 KB LDS.  45 VGPR < 64 -> 2 blocks/CU.
__global__ __launch_bounds__(1024, 8) void gemm1_v2(
    const float* __restrict__ x, const short* __restrict__ A4f,
    short* __restrict__ zb) {
    __shared__ float zsm[16 * 1024];  // 64 KB: [wave][row16][col64]
    const int tid = threadIdx.x, wave = tid >> 6, lane = tid & 63;
    const int m0 = blockIdx.x << 4;
    const int r16 = lane & 15, hi = lane >> 4, kq = hi << 3;
    const float* xp = x + (long)(m0 + r16) * 4000 + kq;
    const short* a4p = A4f + (lane << 3);

    f32x4 acc[4] = {};
#pragma unroll 2
    for (int t = wave; t < 125; t += 16) {
        const int k0 = t << 5;
        f32x4 u0 = *(const f32x4*)(xp + k0);
        f32x4 u1 = *(const f32x4*)(xp + k0 + 4);
        short8 a;
        a[0] = f2bf(u0[0]); a[1] = f2bf(u0[1]);
        a[2] = f2bf(u0[2]); a[3] = f2bf(u0[3]);
        a[4] = f2bf(u1[0]); a[5] = f2bf(u1[1]);
        a[6] = f2bf(u1[2]); a[7] = f2bf(u1[3]);
#pragma unroll
        for (int f = 0; f < 4; ++f) {
            short8 b = *(const short8*)(a4p + (((t << 2) + f) << 9));
            acc[f] = __builtin_amdgcn_mfma_f32_16x16x32_bf16(a, b, acc[f], 0, 0, 0);
        }
    }
    // C/D layout: col = f*16 + (lane&15), row = (lane>>4)*4 + u
    const int prow = hi << 2;
#pragma unroll
    for (int f = 0; f < 4; ++f)
#pragma unroll
        for (int u = 0; u < 4; ++u)
            zsm[wave * 1024 + (prow + u) * 64 + f * 16 + r16] = acc[f][u];
    __syncthreads();
    if (tid < 256) {
        const f32x4* zp = (const f32x4*)zsm;  // 256 f32x4 per wave-slab
        f32x4 s = zp[tid];
#pragma unroll
        for (int w = 1; w < 16; ++w) s += zp[w * 256 + tid];
        s16x4 o;
#pragma unroll
        for (int u = 0; u < 4; ++u) o[u] = f2bf(s[u]);
        const int orow = tid >> 4, ocol = (tid & 15) << 2;
        *(s16x4*)(zb + (m0 + orow) * 64 + ocol) = o;
    }
}

// ---------------- GEMM2: C = zb(8192xK) * B4t(4096xK)^T + bias (proven r8) --
#define BM 128
#define BN 128
#define BK 32

template <int K>
__global__ __launch_bounds__(256) void gemm_bias_kernel(
    const short* __restrict__ A,    // M x K bf16
    const short* __restrict__ Bt,   // N x K bf16
    const float* __restrict__ bias,
    float* __restrict__ C) {
    constexpr int N = 4096;
    __shared__ __align__(16) char smem[16384];  // staging (8K+8K), epilogue 16K
    short* As = (short*)smem;
    short* Bs = (short*)(smem + 8192);
    float* eps = (float*)smem;

    const int tid  = threadIdx.x;
    const int wave = tid >> 6;
    const int lane = tid & 63;

    const int bid = blockIdx.x;
    const int wg  = (bid & 7) * 256 + (bid >> 3);  // 2048 % 8 == 0, bijective
    const int m0 = (wg >> 5) * BM;
    const int n0 = (wg & 31) * BN;

    const int c0i = tid;
    const int c1i = 256 + tid;
    const short* gA0 = A  + (m0 + (c0i >> 2)) * K + ((c0i & 3) << 3);
    const short* gA1 = A  + (m0 + (c1i >> 2)) * K + ((c1i & 3) << 3);
    const short* gB0 = Bt + (n0 + (c0i >> 2)) * K + ((c0i & 3) << 3);
    const short* gB1 = Bt + (n0 + (c1i >> 2)) * K + ((c1i & 3) << 3);
    short* lA0 = As + wave * 512;
    short* lA1 = As + 2048 + wave * 512;
    short* lB0 = Bs + wave * 512;
    short* lB1 = Bs + 2048 + wave * 512;

    const int wr = (wave >> 1) << 6;
    const int wc = (wave & 1) << 6;
    const int r16 = lane & 15;
    const int hi  = lane >> 4;
    const int kq  = hi << 3;

    f32x4 acc[4][4] = {};

    for (int kt = 0; kt < K / BK; ++kt) {
        __builtin_amdgcn_global_load_lds((const __attribute__((address_space(1))) void*)gA0,
                                         (__attribute__((address_space(3))) void*)lA0, 16, 0, 0);
        __builtin_amdgcn_global_load_lds((const __attribute__((address_space(1))) void*)gA1,
                                         (__attribute__((address_space(3))) void*)lA1, 16, 0, 0);
        __builtin_amdgcn_global_load_lds((const __attribute__((address_space(1))) void*)gB0,
                                         (__attribute__((address_space(3))) void*)lB0, 16, 0, 0);
        __builtin_amdgcn_global_load_lds((const __attribute__((address_space(1))) void*)gB1,
                                         (__attribute__((address_space(3))) void*)lB1, 16, 0, 0);
        gA0 += BK; gA1 += BK; gB0 += BK; gB1 += BK;
        __syncthreads();

        short8 a[4], b[4];
#pragma unroll
        for (int f = 0; f < 4; ++f) {
            a[f] = *(const short8*)(As + (wr + f * 16 + r16) * BK + kq);
            b[f] = *(const short8*)(Bs + (wc + f * 16 + r16) * BK + kq);
        }
#pragma unroll
        for (int i = 0; i < 4; ++i)
#pragma unroll
            for (int j = 0; j < 4; ++j)
                acc[i][j] = __builtin_amdgcn_mfma_f32_16x16x32_bf16(
                    a[i], b[j], acc[i][j], 0, 0, 0);
        __syncthreads();
    }

    // ---- epilogue: LDS transpose (barriered) -> 256B-contiguous stores -----
    float* slab = eps + wave * 1024;  // per-wave 4 KB slab
    const f32x4 bzv = *(const f32x4*)(bias + n0 + wc + (r16 << 2));
#pragma unroll
    for (int i = 0; i < 4; ++i) {
        __syncthreads();   // previous iteration's reads (and K-loop) complete
#pragma unroll
        for (int j = 0; j < 4; ++j)
#pragma unroll
            for (int u = 0; u < 4; ++u)
                slab[((hi << 2) + u) * 64 + j * 16 + r16] = acc[i][j][u];
        __syncthreads();   // cross-lane transpose: writes visible to reads
#pragma unroll
        for (int c = 0; c < 4; ++c) {
            const int lrow = (c << 2) + hi;                 // 0..15
            f32x4 v = *(const f32x4*)(slab + lrow * 64 + (r16 << 2));
            v += bzv;
            const long row = m0 + wr + i * 16 + lrow;
            *(f32x4*)(C + row * N + n0 + wc + (r16 << 2)) = v;
        }
    }
}

// ---------------------------------------------------------------------------
extern "C" void kernel_launch(void* const* d_in, const int* in_sizes, int n_in,
                              void* d_out, int out_size, void* d_ws, size_t ws_size,
                              hipStream_t stream) {
    const float* x    = (const float*)d_in[0];
    const float* c0   = (const float*)d_in[1];
    const float* c1   = (const float*)d_in[2];
    const float* c2   = (const float*)d_in[3];
    const float* c3   = (const float*)d_in[4];
    const float* c4   = (const float*)d_in[5];
    const float* c5   = (const float*)d_in[6];
    const float* c6   = (const float*)d_in[7];
    const float* c7   = (const float*)d_in[8];
    const float* bias = (const float*)d_in[9];
    float* out = (float*)d_out;

    char* ws = (char*)d_ws;
    short* zb  = (short*)ws;                               // 8192*64*2 = 1 MiB
    short* A4f = (short*)(ws + (1u << 20));                // 512 KiB (frag-ordered)
    short* B4t = (short*)(ws + (1u << 20) + (512u << 10)); // 4096*64*2 = 512 KiB

    tt_chain_fused<<<1536, 256, 0, stream>>>(c0, c1, c2, c3, c4, c5, c6, c7,
                                             A4f, B4t);
    gemm1_v2<<<512, 1024, 0, stream>>>(x, A4f, zb);
    gemm_bias_kernel<64><<<2048, 256, 0, stream>>>(zb, B4t, bias, out);
}